// Round 15
// baseline (460.979 us; speedup 1.0000x reference)
//
#include <hip/hip_runtime.h>

typedef unsigned short ushort_t;
typedef unsigned int uint_t;
typedef __attribute__((ext_vector_type(8))) short short8;
typedef __attribute__((ext_vector_type(4))) float f32x4;

__device__ __forceinline__ float bf2f(ushort_t u) {
    union { unsigned u; float f; } c; c.u = ((unsigned)u) << 16; return c.f;
}
__device__ __forceinline__ ushort_t f2bf(float f) {
    union { float f; unsigned u; } c; c.f = f;
    unsigned u = c.u;
    u += 0x7fffu + ((u >> 16) & 1u);   // RNE
    return (ushort_t)(u >> 16);
}

// ---------------------------------------------------------------------------
// fp32 -> bf16 stream conversion (x), vectorized: 1 uint (2 bf16) per thread
// ---------------------------------------------------------------------------
__global__ void cvt_f32_bf16(const float2* __restrict__ src, uint_t* __restrict__ dst,
                             int n2) {
    int i = blockIdx.x * blockDim.x + threadIdx.x;
    if (i >= n2) return;
    float2 v = src[i];
    dst[i] = (uint_t)f2bf(v.x) | ((uint_t)f2bf(v.y) << 16);
}

// ---------------------------------------------------------------------------
// CSR build: zero -> histogram -> block scan -> scan bsums -> apply -> scatter
// ---------------------------------------------------------------------------
__global__ void zero_int(int* __restrict__ p, int n) {
    int i = blockIdx.x * blockDim.x + threadIdx.x;
    if (i < n) p[i] = 0;
}

__global__ void zero_f32(float* __restrict__ p, int n) {
    int i = blockIdx.x * blockDim.x + threadIdx.x;
    if (i < n) p[i] = 0.f;
}

__global__ void hist_dst(const int* __restrict__ dst, int* __restrict__ deg, int E) {
    int e = blockIdx.x * blockDim.x + threadIdx.x;
    if (e < E) atomicAdd(&deg[dst[e]], 1);
}

__global__ void scan1(const int* __restrict__ deg, int* __restrict__ rowptr,
                      int* __restrict__ bsum, int N) {
    __shared__ int sh[256];
    int t = threadIdx.x, idx = blockIdx.x * 256 + t;
    sh[t] = (idx < N) ? deg[idx] : 0;
    __syncthreads();
    for (int off = 1; off < 256; off <<= 1) {
        int v = (t >= off) ? sh[t - off] : 0;
        __syncthreads();
        sh[t] += v;
        __syncthreads();
    }
    if (idx < N) rowptr[idx + 1] = sh[t];
    if (t == 255) bsum[blockIdx.x] = sh[255];
}

__global__ void scan2(int* __restrict__ bsum, int nb) {
    __shared__ int sh[512];
    int t = threadIdx.x;
    int orig = (t < nb) ? bsum[t] : 0;
    sh[t] = orig;
    __syncthreads();
    for (int off = 1; off < 512; off <<= 1) {
        int v = (t >= off) ? sh[t - off] : 0;
        __syncthreads();
        sh[t] += v;
        __syncthreads();
    }
    if (t < nb) bsum[t] = sh[t] - orig;   // exclusive
}

__global__ void scan3(int* __restrict__ rowptr, int* __restrict__ cursor,
                      const int* __restrict__ bsum, int N) {
    int idx = blockIdx.x * blockDim.x + threadIdx.x;
    if (idx >= N) return;
    int v = rowptr[idx + 1] + bsum[idx >> 8];
    rowptr[idx + 1] = v;
    if (idx + 1 < N) cursor[idx + 1] = v;
    if (idx == 0) { rowptr[0] = 0; cursor[0] = 0; }
}

__global__ void scatter_edges(const int* __restrict__ src, const int* __restrict__ dst,
                              int* __restrict__ cursor, int* __restrict__ col, int E) {
    int e = blockIdx.x * blockDim.x + threadIdx.x;
    if (e >= E) return;
    int pos = atomicAdd(&cursor[dst[e]], 1);
    col[pos] = src[e];
}

// ---------------------------------------------------------------------------
// CSR gather (bf16 in, bf16 out): agg[i] = h[i] + sum_nbr h.  One wave/node,
// 4B/lane packed bf16 pairs, fp32 accumulate, x4 unrolled edge loop.
// ---------------------------------------------------------------------------
__device__ __forceinline__ float2 upk(uint_t u) {
    float2 r; r.x = bf2f((ushort_t)(u & 0xffffu)); r.y = bf2f((ushort_t)(u >> 16));
    return r;
}

__global__ __launch_bounds__(256) void agg_gather(const ushort_t* __restrict__ h,
                                                  const int* __restrict__ rowptr,
                                                  const int* __restrict__ col,
                                                  ushort_t* __restrict__ agg, int N) {
    int w = (blockIdx.x * 256 + threadIdx.x) >> 6;   // node = wave id
    if (w >= N) return;
    int lane = threadIdx.x & 63;
    const uint_t* hp = (const uint_t*)h;
    float2 acc = upk(hp[(size_t)w * 64 + lane]);
    int st = rowptr[w], en = rowptr[w + 1];
    int e = st;
    for (; e + 4 <= en; e += 4) {
        int s0 = col[e], s1 = col[e + 1], s2 = col[e + 2], s3 = col[e + 3];
        float2 v0 = upk(hp[(size_t)s0 * 64 + lane]);
        float2 v1 = upk(hp[(size_t)s1 * 64 + lane]);
        float2 v2 = upk(hp[(size_t)s2 * 64 + lane]);
        float2 v3 = upk(hp[(size_t)s3 * 64 + lane]);
        acc.x += v0.x + v1.x + v2.x + v3.x;
        acc.y += v0.y + v1.y + v2.y + v3.y;
    }
    for (; e < en; ++e) {
        float2 v = upk(hp[(size_t)col[e] * 64 + lane]);
        acc.x += v.x; acc.y += v.y;
    }
    uint_t o = (uint_t)f2bf(acc.x) | ((uint_t)f2bf(acc.y) << 16);
    ((uint_t*)agg)[(size_t)w * 64 + lane] = o;
}

// ---------------------------------------------------------------------------
// Pack 4 [128,128] fp32 weight matrices into MFMA B-frag layout (bf16,
// single precision -- lo-half dropped, r15).
// out[m][chunk][ct][lane][i] = bf16(W[k][n]),
//   k = chunk*32 + (lane>>4)*8 + i,  n = ct*16 + (lane&15)
// ---------------------------------------------------------------------------
__global__ void pack_w(const float* __restrict__ w0, const float* __restrict__ w1,
                       const float* __restrict__ w2, const float* __restrict__ w3,
                       ushort_t* __restrict__ out) {
    int id = blockIdx.x * blockDim.x + threadIdx.x;   // 4*16384 total
    if (id >= 4 * 16384) return;
    int m = id >> 14, r = id & 16383;
    const float* w = (m == 0) ? w0 : (m == 1) ? w1 : (m == 2) ? w2 : w3;
    int i = r & 7, lane = (r >> 3) & 63, ct = (r >> 9) & 7, ch = r >> 12;
    int k = ch * 32 + ((lane >> 4) << 3) + i;
    int n = ct * 16 + (lane & 15);
    out[m * 16384 + r] = f2bf(w[k * 128 + n]);
}

// ---------------------------------------------------------------------------
// Code branch: per-graph 3-layer MLP + log_softmax(64) -> code_emb fp32 [G,64]
// ---------------------------------------------------------------------------
__global__ void code_branch(const float* __restrict__ cx,
                            const float* __restrict__ w1, const float* __restrict__ b1,
                            const float* __restrict__ w2, const float* __restrict__ b2,
                            const float* __restrict__ w3, const float* __restrict__ b3,
                            float* __restrict__ code_emb) {
    int g = blockIdx.x, j = threadIdx.x;   // 128 threads
    __shared__ float xb[128], h[128];
    xb[j] = cx[(size_t)g * 128 + j];
    __syncthreads();
    float acc = b1[j];
    for (int k = 0; k < 128; ++k) acc += xb[k] * w1[k * 128 + j];
    h[j] = fmaxf(acc, 0.f);
    __syncthreads();
    acc = b2[j];
    for (int k = 0; k < 128; ++k) acc += h[k] * w2[k * 128 + j];
    __syncthreads();
    xb[j] = fmaxf(acc, 0.f);
    __syncthreads();
    if (j < 64) {   // exactly wave 0
        float o = b3[j];
        for (int k = 0; k < 128; ++k) o += xb[k] * w3[k * 64 + j];
        float m = o;
        for (int off = 32; off; off >>= 1) m = fmaxf(m, __shfl_xor(m, off));
        float e = expf(o - m), s = e;
        for (int off = 32; off; off >>= 1) s += __shfl_xor(s, off);
        float lse = m + logf(s);
        code_emb[(size_t)g * 64 + j] = o - lse;
    }
}

// ---------------------------------------------------------------------------
// GEMM (bf16 in / bf16 out / single-bf16 weights): Y = f(A) @ W + bias.
// Zero-barrier core: block = 128 rows; col-split waves (2 col-tiles each);
// 8 B-frags (32 VGPR) hoisted; A double-buffered across 8 subtiles;
// 1 MFMA per (K-chunk, col-tile) -> 8 MFMAs/subtile (was 16 with hi+lo).
// launch_bounds(256,3): footprint B(32)+Adbuf(32)+af(16)+acc(8)+misc ~110
// fits the 170-VGPR cap -> 3 waves/EU without the r13 spill (r13 spilled
// because hi+lo B needed 64 VGPRs; the fix is shrinking B, not the cap).
// BNA: unpack->BN+relu->repack. STATS: fp32 col sum/sumsq via shfl+atomics.
// ---------------------------------------------------------------------------
template <bool RELU, bool BNA, bool STATS>
__global__ __launch_bounds__(256, 3) void gemm128(const ushort_t* __restrict__ A,
                                                  const ushort_t* __restrict__ Bp,
                                                  const float* __restrict__ bias,
                                                  const float* __restrict__ bnp,
                                                  ushort_t* __restrict__ Y,
                                                  float* __restrict__ stats,
                                                  int Nrows) {
    int wave = threadIdx.x >> 6, lane = threadIdx.x & 63;
    int quad = lane >> 4, l16 = lane & 15;
    int rbase = blockIdx.x * 128;

    // ---- hoist this wave's 8 B-frags ----
    const short8* bp = (const short8*)Bp;
    short8 b[4][2];
#pragma unroll
    for (int c = 0; c < 4; ++c)
#pragma unroll
        for (int t = 0; t < 2; ++t)
            b[c][t] = bp[(c * 8 + wave * 2 + t) * 64 + lane];
    float bsv[2] = { bias[(wave * 2) * 16 + l16], bias[(wave * 2 + 1) * 16 + l16] };

    float cs[2] = {0.f, 0.f}, css[2] = {0.f, 0.f};
    short8 a[2][4];   // double buffer: 4 K-chunk frags per subtile

    // prefetch sub 0
    {
        int arow = rbase + l16;
        if (arow < Nrows) {
            const short8* ap = (const short8*)(A + (size_t)arow * 128);
#pragma unroll
            for (int c = 0; c < 4; ++c) a[0][c] = ap[c * 4 + quad];
        } else {
#pragma unroll
            for (int c = 0; c < 4; ++c) a[0][c] = (short8)0;
        }
    }

#pragma unroll 2
    for (int sub = 0; sub < 8; ++sub) {
        int cur = sub & 1, nxt = cur ^ 1;
        if (sub + 1 < 8) {
            int arow = rbase + (sub + 1) * 16 + l16;
            if (arow < Nrows) {
                const short8* ap = (const short8*)(A + (size_t)arow * 128);
#pragma unroll
                for (int c = 0; c < 4; ++c) a[nxt][c] = ap[c * 4 + quad];
            } else {
#pragma unroll
                for (int c = 0; c < 4; ++c) a[nxt][c] = (short8)0;
            }
        }
        short8 af[4];
#pragma unroll
        for (int c = 0; c < 4; ++c) {
            if (BNA) {
                int cbase = c * 32 + quad * 8;
#pragma unroll
                for (int i = 0; i < 8; ++i) {
                    float x = bf2f((ushort_t)a[cur][c][i]);
                    x = fmaxf(x * bnp[cbase + i] + bnp[128 + cbase + i], 0.f);
                    af[c][i] = (short)f2bf(x);
                }
            } else {
                af[c] = a[cur][c];
            }
        }
        f32x4 acc[2] = {};
#pragma unroll
        for (int c = 0; c < 4; ++c)
#pragma unroll
            for (int t = 0; t < 2; ++t)
                acc[t] = __builtin_amdgcn_mfma_f32_16x16x32_bf16(af[c], b[c][t], acc[t], 0, 0, 0);
#pragma unroll
        for (int t = 0; t < 2; ++t) {
            int colj = (wave * 2 + t) * 16 + l16;
#pragma unroll
            for (int i = 0; i < 4; ++i) {
                int row = rbase + sub * 16 + quad * 4 + i;
                if (row < Nrows) {
                    float v = acc[t][i] + bsv[t];
                    if (RELU) v = fmaxf(v, 0.f);
                    Y[(size_t)row * 128 + colj] = f2bf(v);
                    if (STATS) { cs[t] += v; css[t] += v * v; }
                }
            }
        }
    }
    if (STATS) {
#pragma unroll
        for (int t = 0; t < 2; ++t) {
            float s = cs[t], q = css[t];
            s += __shfl_xor(s, 16); q += __shfl_xor(q, 16);
            s += __shfl_xor(s, 32); q += __shfl_xor(q, 32);
            if (quad == 0) {
                int colj = (wave * 2 + t) * 16 + l16;
                unsafeAtomicAdd(&stats[colj], s);
                unsafeAtomicAdd(&stats[128 + colj], q);
            }
        }
    }
}

// ---------------------------------------------------------------------------
// BN params from fused stats: bnp[j]=gamma*rsqrt(var+eps), bnp[128+j]=beta-mu*sc
// ---------------------------------------------------------------------------
__global__ void bn_final(const float* __restrict__ stats,
                         const float* __restrict__ gamma, const float* __restrict__ beta,
                         float* __restrict__ bnp, int Nrows) {
    int j = threadIdx.x;   // 128
    float s = stats[j], ss = stats[128 + j];
    float inv_n = 1.0f / (float)Nrows;
    float mu = s * inv_n;
    float var = ss * inv_n - mu * mu;
    var = fmaxf(var, 0.f);
    float rs = rsqrtf(var + 1e-5f);
    float sc = gamma[j] * rs;
    bnp[j] = sc;
    bnp[128 + j] = beta[j] - mu * sc;
}

// ---------------------------------------------------------------------------
// Fused pool (sorted-batch binary search, bf16 H) + head MLP + concat +
// final log_softmax  (fp32 math throughout)
// ---------------------------------------------------------------------------
__global__ void head_kernel(const ushort_t* __restrict__ H, const int* __restrict__ batch,
                            const float* __restrict__ code_emb,
                            const float* __restrict__ l1w, const float* __restrict__ l1b,
                            const float* __restrict__ l2w, const float* __restrict__ l2b,
                            const float* __restrict__ finw, const float* __restrict__ finb,
                            float* __restrict__ out, int Nrows) {
    int g = blockIdx.x, j = threadIdx.x;   // 128 threads
    int lo = 0, hi = Nrows;
    while (lo < hi) { int m = (lo + hi) >> 1; if (batch[m] < g) lo = m + 1; else hi = m; }
    int st = lo;
    hi = Nrows;
    while (lo < hi) { int m = (lo + hi) >> 1; if (batch[m] <= g) lo = m + 1; else hi = m; }
    int en = lo;

    float p = 0.f;
    int i = st;
    for (; i + 4 <= en; i += 4) {
        float v0 = bf2f(H[(size_t)i * 128 + j]);
        float v1 = bf2f(H[(size_t)(i + 1) * 128 + j]);
        float v2 = bf2f(H[(size_t)(i + 2) * 128 + j]);
        float v3 = bf2f(H[(size_t)(i + 3) * 128 + j]);
        p += v0 + v1 + v2 + v3;
    }
    for (; i < en; ++i) p += bf2f(H[(size_t)i * 128 + j]);

    __shared__ float pb[128], t[128], v[128], lg[2];
    pb[j] = p;
    __syncthreads();
    float acc = l1b[j];
    for (int k = 0; k < 128; ++k) acc += pb[k] * l1w[k * 128 + j];
    t[j] = fmaxf(acc, 0.f);
    __syncthreads();
    if (j < 64) {
        float a2 = l2b[j];
        for (int k = 0; k < 128; ++k) a2 += t[k] * l2w[k * 64 + j];
        v[64 + j] = a2;                       // trans_emb
        v[j] = code_emb[(size_t)g * 64 + j];  // code_emb
    }
    __syncthreads();
    if (j < 2) {
        float a3 = finb[j];
        for (int k = 0; k < 128; ++k) a3 += v[k] * finw[k * 2 + j];
        lg[j] = a3;
    }
    __syncthreads();
    if (j == 0) {
        float a = lg[0], b = lg[1];
        float m = fmaxf(a, b);
        float lse = m + logf(expf(a - m) + expf(b - m));
        out[g * 2 + 0] = a - lse;
        out[g * 2 + 1] = b - lse;
    }
}

// ---------------------------------------------------------------------------

extern "C" void kernel_launch(void* const* d_in, const int* in_sizes, int n_in,
                              void* d_out, int out_size, void* d_ws, size_t ws_size,
                              hipStream_t stream) {
    (void)n_in; (void)out_size; (void)ws_size;
    const float* x     = (const float*)d_in[0];
    const int*   ei    = (const int*)d_in[1];
    const int*   batch = (const int*)d_in[2];
    const float* cx    = (const float*)d_in[3];
    const float* c1w1  = (const float*)d_in[4];
    const float* c1b1  = (const float*)d_in[5];
    const float* c1g   = (const float*)d_in[6];
    const float* c1be  = (const float*)d_in[7];
    const float* c1w2  = (const float*)d_in[8];
    const float* c1b2  = (const float*)d_in[9];
    const float* c2w1  = (const float*)d_in[10];
    const float* c2b1  = (const float*)d_in[11];
    const float* c2g   = (const float*)d_in[12];
    const float* c2be  = (const float*)d_in[13];
    const float* c2w2  = (const float*)d_in[14];
    const float* c2b2  = (const float*)d_in[15];
    const float* gl1w  = (const float*)d_in[16];
    const float* gl1b  = (const float*)d_in[17];
    const float* gl2w  = (const float*)d_in[18];
    const float* gl2b  = (const float*)d_in[19];
    const float* fc1w  = (const float*)d_in[20];
    const float* fc1b  = (const float*)d_in[21];
    const float* fc2w  = (const float*)d_in[22];
    const float* fc2b  = (const float*)d_in[23];
    const float* fc3w  = (const float*)d_in[24];
    const float* fc3b  = (const float*)d_in[25];
    const float* finw  = (const float*)d_in[26];
    const float* finb  = (const float*)d_in[27];

    const int N = in_sizes[0] / 128;
    const int E = in_sizes[1] / 2;
    const int G = in_sizes[3] / 128;
    const int* src = ei;
    const int* dst = ei + E;

    // workspace layout (16B-aligned)
    ushort_t* bufA = (ushort_t*)d_ws;                  // N*128 bf16
    ushort_t* bufB = bufA + (size_t)N * 128;           // N*128 bf16
    float* code_emb = (float*)(bufB + (size_t)N * 128); // G*64
    float* statsA   = code_emb + (size_t)G * 64;       // 256
    float* statsB   = statsA + 256;                    // 256
    float* bnp      = statsB + 256;                    // 256
    ushort_t* packW = (ushort_t*)(bnp + 256);          // 4*16384 ushorts
    int* rowptr = (int*)(packW + 4 * 16384);           // N+1
    int* tmp    = rowptr + (N + 1);                    // N+1 (deg, then cursor)
    int* bsum   = tmp + (N + 1);                       // 512
    int* col    = bsum + 512;                          // E

    const int gmm = (N + 127) / 128;
    const int nb  = (N + 255) / 256;                   // scan chunks (<=512)
    const int gag = (N * 64 + 255) / 256;              // gather: 1 wave/node

    // ---- x -> bf16 (into bufB; consumed by conv1 gather) ----
    cvt_f32_bf16<<<(N * 64 + 255) / 256, 256, 0, stream>>>(
        (const float2*)x, (uint_t*)bufB, N * 64);

    // ---- CSR build + init (once) ----
    zero_int<<<(N + 256) / 256, 256, 0, stream>>>(tmp, N + 1);
    zero_f32<<<2, 256, 0, stream>>>(statsA, 512);      // statsA+statsB
    hist_dst<<<(E + 255) / 256, 256, 0, stream>>>(dst, tmp, E);
    scan1<<<nb, 256, 0, stream>>>(tmp, rowptr, bsum, N);
    scan2<<<1, 512, 0, stream>>>(bsum, nb);
    scan3<<<(N + 255) / 256, 256, 0, stream>>>(rowptr, tmp, bsum, N);
    scatter_edges<<<(E + 255) / 256, 256, 0, stream>>>(src, dst, tmp, col, E);

    pack_w<<<(4 * 16384 + 255) / 256, 256, 0, stream>>>(c1w1, c1w2, c2w1, c2w2, packW);
    code_branch<<<G, 128, 0, stream>>>(cx, fc1w, fc1b, fc2w, fc2b, fc3w, fc3b, code_emb);

    // ---- conv1 ----
    agg_gather<<<gag, 256, 0, stream>>>(bufB, rowptr, col, bufA, N);            // agg1
    gemm128<false, false, true><<<gmm, 256, 0, stream>>>(
        bufA, packW, c1b1, nullptr, bufB, statsA, N);                           // y1
    bn_final<<<1, 128, 0, stream>>>(statsA, c1g, c1be, bnp, N);
    gemm128<true, true, false><<<gmm, 256, 0, stream>>>(
        bufB, packW + 16384, c1b2, bnp, bufA, nullptr, N);                      // h1

    // ---- conv2 ----
    agg_gather<<<gag, 256, 0, stream>>>(bufA, rowptr, col, bufB, N);            // agg2
    gemm128<false, false, true><<<gmm, 256, 0, stream>>>(
        bufB, packW + 2 * 16384, c2b1, nullptr, bufA, statsB, N);               // y2
    bn_final<<<1, 128, 0, stream>>>(statsB, c2g, c2be, bnp, N);
    gemm128<true, true, false><<<gmm, 256, 0, stream>>>(
        bufA, packW + 3 * 16384, c2b2, bnp, bufB, nullptr, N);                  // h2

    head_kernel<<<G, 128, 0, stream>>>(bufB, batch, code_emb,
                                       gl1w, gl1b, gl2w, gl2b, finw, finb,
                                       (float*)d_out, N);
}

// Round 16
// 438.036 us; speedup vs baseline: 1.0524x; 1.0524x over previous
//
#include <hip/hip_runtime.h>

typedef unsigned short ushort_t;
typedef unsigned int uint_t;
typedef __attribute__((ext_vector_type(8))) short short8;
typedef __attribute__((ext_vector_type(4))) float f32x4;

__device__ __forceinline__ float bf2f(ushort_t u) {
    union { unsigned u; float f; } c; c.u = ((unsigned)u) << 16; return c.f;
}
__device__ __forceinline__ ushort_t f2bf(float f) {
    union { float f; unsigned u; } c; c.f = f;
    unsigned u = c.u;
    u += 0x7fffu + ((u >> 16) & 1u);   // RNE
    return (ushort_t)(u >> 16);
}

// ---------------------------------------------------------------------------
// fp32 -> bf16 stream conversion (x), vectorized: 1 uint (2 bf16) per thread
// ---------------------------------------------------------------------------
__global__ void cvt_f32_bf16(const float2* __restrict__ src, uint_t* __restrict__ dst,
                             int n2) {
    int i = blockIdx.x * blockDim.x + threadIdx.x;
    if (i >= n2) return;
    float2 v = src[i];
    dst[i] = (uint_t)f2bf(v.x) | ((uint_t)f2bf(v.y) << 16);
}

// ---------------------------------------------------------------------------
// CSR build: zero -> histogram -> block scan -> scan bsums -> apply -> scatter
// ---------------------------------------------------------------------------
__global__ void zero_int(int* __restrict__ p, int n) {
    int i = blockIdx.x * blockDim.x + threadIdx.x;
    if (i < n) p[i] = 0;
}

__global__ void zero_f32(float* __restrict__ p, int n) {
    int i = blockIdx.x * blockDim.x + threadIdx.x;
    if (i < n) p[i] = 0.f;
}

__global__ void hist_dst(const int* __restrict__ dst, int* __restrict__ deg, int E) {
    int e = blockIdx.x * blockDim.x + threadIdx.x;
    if (e < E) atomicAdd(&deg[dst[e]], 1);
}

__global__ void scan1(const int* __restrict__ deg, int* __restrict__ rowptr,
                      int* __restrict__ bsum, int N) {
    __shared__ int sh[256];
    int t = threadIdx.x, idx = blockIdx.x * 256 + t;
    sh[t] = (idx < N) ? deg[idx] : 0;
    __syncthreads();
    for (int off = 1; off < 256; off <<= 1) {
        int v = (t >= off) ? sh[t - off] : 0;
        __syncthreads();
        sh[t] += v;
        __syncthreads();
    }
    if (idx < N) rowptr[idx + 1] = sh[t];
    if (t == 255) bsum[blockIdx.x] = sh[255];
}

__global__ void scan2(int* __restrict__ bsum, int nb) {
    __shared__ int sh[512];
    int t = threadIdx.x;
    int orig = (t < nb) ? bsum[t] : 0;
    sh[t] = orig;
    __syncthreads();
    for (int off = 1; off < 512; off <<= 1) {
        int v = (t >= off) ? sh[t - off] : 0;
        __syncthreads();
        sh[t] += v;
        __syncthreads();
    }
    if (t < nb) bsum[t] = sh[t] - orig;   // exclusive
}

__global__ void scan3(int* __restrict__ rowptr, int* __restrict__ cursor,
                      const int* __restrict__ bsum, int N) {
    int idx = blockIdx.x * blockDim.x + threadIdx.x;
    if (idx >= N) return;
    int v = rowptr[idx + 1] + bsum[idx >> 8];
    rowptr[idx + 1] = v;
    if (idx + 1 < N) cursor[idx + 1] = v;
    if (idx == 0) { rowptr[0] = 0; cursor[0] = 0; }
}

__global__ void scatter_edges(const int* __restrict__ src, const int* __restrict__ dst,
                              int* __restrict__ cursor, int* __restrict__ col, int E) {
    int e = blockIdx.x * blockDim.x + threadIdx.x;
    if (e >= E) return;
    int pos = atomicAdd(&cursor[dst[e]], 1);
    col[pos] = src[e];
}

// ---------------------------------------------------------------------------
// CSR gather (bf16 in, bf16 out): agg[i] = h[i] + sum_nbr h.  One wave/node,
// 4B/lane packed bf16 pairs, fp32 accumulate, x4 unrolled edge loop.
// ---------------------------------------------------------------------------
__device__ __forceinline__ float2 upk(uint_t u) {
    float2 r; r.x = bf2f((ushort_t)(u & 0xffffu)); r.y = bf2f((ushort_t)(u >> 16));
    return r;
}

__global__ __launch_bounds__(256) void agg_gather(const ushort_t* __restrict__ h,
                                                  const int* __restrict__ rowptr,
                                                  const int* __restrict__ col,
                                                  ushort_t* __restrict__ agg, int N) {
    int w = (blockIdx.x * 256 + threadIdx.x) >> 6;   // node = wave id
    if (w >= N) return;
    int lane = threadIdx.x & 63;
    const uint_t* hp = (const uint_t*)h;
    float2 acc = upk(hp[(size_t)w * 64 + lane]);
    int st = rowptr[w], en = rowptr[w + 1];
    int e = st;
    for (; e + 4 <= en; e += 4) {
        int s0 = col[e], s1 = col[e + 1], s2 = col[e + 2], s3 = col[e + 3];
        float2 v0 = upk(hp[(size_t)s0 * 64 + lane]);
        float2 v1 = upk(hp[(size_t)s1 * 64 + lane]);
        float2 v2 = upk(hp[(size_t)s2 * 64 + lane]);
        float2 v3 = upk(hp[(size_t)s3 * 64 + lane]);
        acc.x += v0.x + v1.x + v2.x + v3.x;
        acc.y += v0.y + v1.y + v2.y + v3.y;
    }
    for (; e < en; ++e) {
        float2 v = upk(hp[(size_t)col[e] * 64 + lane]);
        acc.x += v.x; acc.y += v.y;
    }
    uint_t o = (uint_t)f2bf(acc.x) | ((uint_t)f2bf(acc.y) << 16);
    ((uint_t*)agg)[(size_t)w * 64 + lane] = o;
}

// ---------------------------------------------------------------------------
// Pack 4 [128,128] fp32 weight matrices into MFMA B-frag layout (bf16,
// single precision).
// out[m][chunk][ct][lane][i] = bf16(W[k][n]),
//   k = chunk*32 + (lane>>4)*8 + i,  n = ct*16 + (lane&15)
// ---------------------------------------------------------------------------
__global__ void pack_w(const float* __restrict__ w0, const float* __restrict__ w1,
                       const float* __restrict__ w2, const float* __restrict__ w3,
                       ushort_t* __restrict__ out) {
    int id = blockIdx.x * blockDim.x + threadIdx.x;   // 4*16384 total
    if (id >= 4 * 16384) return;
    int m = id >> 14, r = id & 16383;
    const float* w = (m == 0) ? w0 : (m == 1) ? w1 : (m == 2) ? w2 : w3;
    int i = r & 7, lane = (r >> 3) & 63, ct = (r >> 9) & 7, ch = r >> 12;
    int k = ch * 32 + ((lane >> 4) << 3) + i;
    int n = ct * 16 + (lane & 15);
    out[m * 16384 + r] = f2bf(w[k * 128 + n]);
}

// ---------------------------------------------------------------------------
// Code branch: per-graph 3-layer MLP + log_softmax(64) -> code_emb fp32 [G,64]
// ---------------------------------------------------------------------------
__global__ void code_branch(const float* __restrict__ cx,
                            const float* __restrict__ w1, const float* __restrict__ b1,
                            const float* __restrict__ w2, const float* __restrict__ b2,
                            const float* __restrict__ w3, const float* __restrict__ b3,
                            float* __restrict__ code_emb) {
    int g = blockIdx.x, j = threadIdx.x;   // 128 threads
    __shared__ float xb[128], h[128];
    xb[j] = cx[(size_t)g * 128 + j];
    __syncthreads();
    float acc = b1[j];
    for (int k = 0; k < 128; ++k) acc += xb[k] * w1[k * 128 + j];
    h[j] = fmaxf(acc, 0.f);
    __syncthreads();
    acc = b2[j];
    for (int k = 0; k < 128; ++k) acc += h[k] * w2[k * 128 + j];
    __syncthreads();
    xb[j] = fmaxf(acc, 0.f);
    __syncthreads();
    if (j < 64) {   // exactly wave 0
        float o = b3[j];
        for (int k = 0; k < 128; ++k) o += xb[k] * w3[k * 64 + j];
        float m = o;
        for (int off = 32; off; off >>= 1) m = fmaxf(m, __shfl_xor(m, off));
        float e = expf(o - m), s = e;
        for (int off = 32; off; off >>= 1) s += __shfl_xor(s, off);
        float lse = m + logf(s);
        code_emb[(size_t)g * 64 + j] = o - lse;
    }
}

// ---------------------------------------------------------------------------
// GEMM (bf16 in / bf16 out / single-bf16 weights): Y = f(A) @ W + bias.
// Zero-barrier core: block = 128 rows; col-split waves (2 col-tiles each);
// 8 B-frags (32 VGPR) hoisted; A double-buffered across 8 subtiles;
// 1 MFMA per (K-chunk, col-tile).
// launch_bounds(256,2) is FINAL. Sweep (4 data points):
//   (256,2): clean, 446us total (r14) | (256,3): +15us/gemm spill-ish
//   penalty BOTH with 64-VGPR B (r13, WRITE 40.8MB) and 32-VGPR B (r15) |
//   (256,4): compiler drops B, FETCH 187MB, 109us/gemm (r12).
// BNA: unpack->BN+relu->repack. STATS: fp32 col sum/sumsq via shfl+atomics.
// ---------------------------------------------------------------------------
template <bool RELU, bool BNA, bool STATS>
__global__ __launch_bounds__(256, 2) void gemm128(const ushort_t* __restrict__ A,
                                                  const ushort_t* __restrict__ Bp,
                                                  const float* __restrict__ bias,
                                                  const float* __restrict__ bnp,
                                                  ushort_t* __restrict__ Y,
                                                  float* __restrict__ stats,
                                                  int Nrows) {
    int wave = threadIdx.x >> 6, lane = threadIdx.x & 63;
    int quad = lane >> 4, l16 = lane & 15;
    int rbase = blockIdx.x * 128;

    // ---- hoist this wave's 8 B-frags ----
    const short8* bp = (const short8*)Bp;
    short8 b[4][2];
#pragma unroll
    for (int c = 0; c < 4; ++c)
#pragma unroll
        for (int t = 0; t < 2; ++t)
            b[c][t] = bp[(c * 8 + wave * 2 + t) * 64 + lane];
    float bsv[2] = { bias[(wave * 2) * 16 + l16], bias[(wave * 2 + 1) * 16 + l16] };

    float cs[2] = {0.f, 0.f}, css[2] = {0.f, 0.f};
    short8 a[2][4];   // double buffer: 4 K-chunk frags per subtile

    // prefetch sub 0
    {
        int arow = rbase + l16;
        if (arow < Nrows) {
            const short8* ap = (const short8*)(A + (size_t)arow * 128);
#pragma unroll
            for (int c = 0; c < 4; ++c) a[0][c] = ap[c * 4 + quad];
        } else {
#pragma unroll
            for (int c = 0; c < 4; ++c) a[0][c] = (short8)0;
        }
    }

#pragma unroll 2
    for (int sub = 0; sub < 8; ++sub) {
        int cur = sub & 1, nxt = cur ^ 1;
        if (sub + 1 < 8) {
            int arow = rbase + (sub + 1) * 16 + l16;
            if (arow < Nrows) {
                const short8* ap = (const short8*)(A + (size_t)arow * 128);
#pragma unroll
                for (int c = 0; c < 4; ++c) a[nxt][c] = ap[c * 4 + quad];
            } else {
#pragma unroll
                for (int c = 0; c < 4; ++c) a[nxt][c] = (short8)0;
            }
        }
        short8 af[4];
#pragma unroll
        for (int c = 0; c < 4; ++c) {
            if (BNA) {
                int cbase = c * 32 + quad * 8;
#pragma unroll
                for (int i = 0; i < 8; ++i) {
                    float x = bf2f((ushort_t)a[cur][c][i]);
                    x = fmaxf(x * bnp[cbase + i] + bnp[128 + cbase + i], 0.f);
                    af[c][i] = (short)f2bf(x);
                }
            } else {
                af[c] = a[cur][c];
            }
        }
        f32x4 acc[2] = {};
#pragma unroll
        for (int c = 0; c < 4; ++c)
#pragma unroll
            for (int t = 0; t < 2; ++t)
                acc[t] = __builtin_amdgcn_mfma_f32_16x16x32_bf16(af[c], b[c][t], acc[t], 0, 0, 0);
#pragma unroll
        for (int t = 0; t < 2; ++t) {
            int colj = (wave * 2 + t) * 16 + l16;
#pragma unroll
            for (int i = 0; i < 4; ++i) {
                int row = rbase + sub * 16 + quad * 4 + i;
                if (row < Nrows) {
                    float v = acc[t][i] + bsv[t];
                    if (RELU) v = fmaxf(v, 0.f);
                    Y[(size_t)row * 128 + colj] = f2bf(v);
                    if (STATS) { cs[t] += v; css[t] += v * v; }
                }
            }
        }
    }
    if (STATS) {
#pragma unroll
        for (int t = 0; t < 2; ++t) {
            float s = cs[t], q = css[t];
            s += __shfl_xor(s, 16); q += __shfl_xor(q, 16);
            s += __shfl_xor(s, 32); q += __shfl_xor(q, 32);
            if (quad == 0) {
                int colj = (wave * 2 + t) * 16 + l16;
                unsafeAtomicAdd(&stats[colj], s);
                unsafeAtomicAdd(&stats[128 + colj], q);
            }
        }
    }
}

// ---------------------------------------------------------------------------
// BN params from fused stats: bnp[j]=gamma*rsqrt(var+eps), bnp[128+j]=beta-mu*sc
// ---------------------------------------------------------------------------
__global__ void bn_final(const float* __restrict__ stats,
                         const float* __restrict__ gamma, const float* __restrict__ beta,
                         float* __restrict__ bnp, int Nrows) {
    int j = threadIdx.x;   // 128
    float s = stats[j], ss = stats[128 + j];
    float inv_n = 1.0f / (float)Nrows;
    float mu = s * inv_n;
    float var = ss * inv_n - mu * mu;
    var = fmaxf(var, 0.f);
    float rs = rsqrtf(var + 1e-5f);
    float sc = gamma[j] * rs;
    bnp[j] = sc;
    bnp[128 + j] = beta[j] - mu * sc;
}

// ---------------------------------------------------------------------------
// Fused pool (sorted-batch binary search, bf16 H) + head MLP + concat +
// final log_softmax  (fp32 math throughout)
// ---------------------------------------------------------------------------
__global__ void head_kernel(const ushort_t* __restrict__ H, const int* __restrict__ batch,
                            const float* __restrict__ code_emb,
                            const float* __restrict__ l1w, const float* __restrict__ l1b,
                            const float* __restrict__ l2w, const float* __restrict__ l2b,
                            const float* __restrict__ finw, const float* __restrict__ finb,
                            float* __restrict__ out, int Nrows) {
    int g = blockIdx.x, j = threadIdx.x;   // 128 threads
    int lo = 0, hi = Nrows;
    while (lo < hi) { int m = (lo + hi) >> 1; if (batch[m] < g) lo = m + 1; else hi = m; }
    int st = lo;
    hi = Nrows;
    while (lo < hi) { int m = (lo + hi) >> 1; if (batch[m] <= g) lo = m + 1; else hi = m; }
    int en = lo;

    float p = 0.f;
    int i = st;
    for (; i + 4 <= en; i += 4) {
        float v0 = bf2f(H[(size_t)i * 128 + j]);
        float v1 = bf2f(H[(size_t)(i + 1) * 128 + j]);
        float v2 = bf2f(H[(size_t)(i + 2) * 128 + j]);
        float v3 = bf2f(H[(size_t)(i + 3) * 128 + j]);
        p += v0 + v1 + v2 + v3;
    }
    for (; i < en; ++i) p += bf2f(H[(size_t)i * 128 + j]);

    __shared__ float pb[128], t[128], v[128], lg[2];
    pb[j] = p;
    __syncthreads();
    float acc = l1b[j];
    for (int k = 0; k < 128; ++k) acc += pb[k] * l1w[k * 128 + j];
    t[j] = fmaxf(acc, 0.f);
    __syncthreads();
    if (j < 64) {
        float a2 = l2b[j];
        for (int k = 0; k < 128; ++k) a2 += t[k] * l2w[k * 64 + j];
        v[64 + j] = a2;                       // trans_emb
        v[j] = code_emb[(size_t)g * 64 + j];  // code_emb
    }
    __syncthreads();
    if (j < 2) {
        float a3 = finb[j];
        for (int k = 0; k < 128; ++k) a3 += v[k] * finw[k * 2 + j];
        lg[j] = a3;
    }
    __syncthreads();
    if (j == 0) {
        float a = lg[0], b = lg[1];
        float m = fmaxf(a, b);
        float lse = m + logf(expf(a - m) + expf(b - m));
        out[g * 2 + 0] = a - lse;
        out[g * 2 + 1] = b - lse;
    }
}

// ---------------------------------------------------------------------------

extern "C" void kernel_launch(void* const* d_in, const int* in_sizes, int n_in,
                              void* d_out, int out_size, void* d_ws, size_t ws_size,
                              hipStream_t stream) {
    (void)n_in; (void)out_size; (void)ws_size;
    const float* x     = (const float*)d_in[0];
    const int*   ei    = (const int*)d_in[1];
    const int*   batch = (const int*)d_in[2];
    const float* cx    = (const float*)d_in[3];
    const float* c1w1  = (const float*)d_in[4];
    const float* c1b1  = (const float*)d_in[5];
    const float* c1g   = (const float*)d_in[6];
    const float* c1be  = (const float*)d_in[7];
    const float* c1w2  = (const float*)d_in[8];
    const float* c1b2  = (const float*)d_in[9];
    const float* c2w1  = (const float*)d_in[10];
    const float* c2b1  = (const float*)d_in[11];
    const float* c2g   = (const float*)d_in[12];
    const float* c2be  = (const float*)d_in[13];
    const float* c2w2  = (const float*)d_in[14];
    const float* c2b2  = (const float*)d_in[15];
    const float* gl1w  = (const float*)d_in[16];
    const float* gl1b  = (const float*)d_in[17];
    const float* gl2w  = (const float*)d_in[18];
    const float* gl2b  = (const float*)d_in[19];
    const float* fc1w  = (const float*)d_in[20];
    const float* fc1b  = (const float*)d_in[21];
    const float* fc2w  = (const float*)d_in[22];
    const float* fc2b  = (const float*)d_in[23];
    const float* fc3w  = (const float*)d_in[24];
    const float* fc3b  = (const float*)d_in[25];
    const float* finw  = (const float*)d_in[26];
    const float* finb  = (const float*)d_in[27];

    const int N = in_sizes[0] / 128;
    const int E = in_sizes[1] / 2;
    const int G = in_sizes[3] / 128;
    const int* src = ei;
    const int* dst = ei + E;

    // workspace layout (16B-aligned)
    ushort_t* bufA = (ushort_t*)d_ws;                  // N*128 bf16
    ushort_t* bufB = bufA + (size_t)N * 128;           // N*128 bf16
    float* code_emb = (float*)(bufB + (size_t)N * 128); // G*64
    float* statsA   = code_emb + (size_t)G * 64;       // 256
    float* statsB   = statsA + 256;                    // 256
    float* bnp      = statsB + 256;                    // 256
    ushort_t* packW = (ushort_t*)(bnp + 256);          // 4*16384 ushorts
    int* rowptr = (int*)(packW + 4 * 16384);           // N+1
    int* tmp    = rowptr + (N + 1);                    // N+1 (deg, then cursor)
    int* bsum   = tmp + (N + 1);                       // 512
    int* col    = bsum + 512;                          // E

    const int gmm = (N + 127) / 128;
    const int nb  = (N + 255) / 256;                   // scan chunks (<=512)
    const int gag = (N * 64 + 255) / 256;              // gather: 1 wave/node

    // ---- x -> bf16 (into bufB; consumed by conv1 gather) ----
    cvt_f32_bf16<<<(N * 64 + 255) / 256, 256, 0, stream>>>(
        (const float2*)x, (uint_t*)bufB, N * 64);

    // ---- CSR build + init (once) ----
    zero_int<<<(N + 256) / 256, 256, 0, stream>>>(tmp, N + 1);
    zero_f32<<<2, 256, 0, stream>>>(statsA, 512);      // statsA+statsB
    hist_dst<<<(E + 255) / 256, 256, 0, stream>>>(dst, tmp, E);
    scan1<<<nb, 256, 0, stream>>>(tmp, rowptr, bsum, N);
    scan2<<<1, 512, 0, stream>>>(bsum, nb);
    scan3<<<(N + 255) / 256, 256, 0, stream>>>(rowptr, tmp, bsum, N);
    scatter_edges<<<(E + 255) / 256, 256, 0, stream>>>(src, dst, tmp, col, E);

    pack_w<<<(4 * 16384 + 255) / 256, 256, 0, stream>>>(c1w1, c1w2, c2w1, c2w2, packW);
    code_branch<<<G, 128, 0, stream>>>(cx, fc1w, fc1b, fc2w, fc2b, fc3w, fc3b, code_emb);

    // ---- conv1 ----
    agg_gather<<<gag, 256, 0, stream>>>(bufB, rowptr, col, bufA, N);            // agg1
    gemm128<false, false, true><<<gmm, 256, 0, stream>>>(
        bufA, packW, c1b1, nullptr, bufB, statsA, N);                           // y1
    bn_final<<<1, 128, 0, stream>>>(statsA, c1g, c1be, bnp, N);
    gemm128<true, true, false><<<gmm, 256, 0, stream>>>(
        bufB, packW + 16384, c1b2, bnp, bufA, nullptr, N);                      // h1

    // ---- conv2 ----
    agg_gather<<<gag, 256, 0, stream>>>(bufA, rowptr, col, bufB, N);            // agg2
    gemm128<false, false, true><<<gmm, 256, 0, stream>>>(
        bufB, packW + 2 * 16384, c2b1, nullptr, bufA, statsB, N);               // y2
    bn_final<<<1, 128, 0, stream>>>(statsB, c2g, c2be, bnp, N);
    gemm128<true, true, false><<<gmm, 256, 0, stream>>>(
        bufA, packW + 3 * 16384, c2b2, bnp, bufB, nullptr, N);                  // h2

    head_kernel<<<G, 128, 0, stream>>>(bufB, batch, code_emb,
                                       gl1w, gl1b, gl2w, gl2b, finw, finb,
                                       (float*)d_out, N);
}

// Round 17
// 429.743 us; speedup vs baseline: 1.0727x; 1.0193x over previous
//
#include <hip/hip_runtime.h>

typedef unsigned short ushort_t;
typedef unsigned int uint_t;
typedef __attribute__((ext_vector_type(8))) short short8;
typedef __attribute__((ext_vector_type(4))) float f32x4;

__device__ __forceinline__ float bf2f(ushort_t u) {
    union { unsigned u; float f; } c; c.u = ((unsigned)u) << 16; return c.f;
}
__device__ __forceinline__ ushort_t f2bf(float f) {
    union { float f; unsigned u; } c; c.f = f;
    unsigned u = c.u;
    u += 0x7fffu + ((u >> 16) & 1u);   // RNE
    return (ushort_t)(u >> 16);
}

// ---------------------------------------------------------------------------
// fp32 -> bf16 stream conversion (x), vectorized: 1 uint (2 bf16) per thread
// ---------------------------------------------------------------------------
__global__ void cvt_f32_bf16(const float2* __restrict__ src, uint_t* __restrict__ dst,
                             int n2) {
    int i = blockIdx.x * blockDim.x + threadIdx.x;
    if (i >= n2) return;
    float2 v = src[i];
    dst[i] = (uint_t)f2bf(v.x) | ((uint_t)f2bf(v.y) << 16);
}

// ---------------------------------------------------------------------------
// Combined init: zero deg[N+1] (int) and stats[512] (fp32) in one launch
// ---------------------------------------------------------------------------
__global__ void init_zero(int* __restrict__ pi, int ni, float* __restrict__ pf, int nf) {
    int i = blockIdx.x * blockDim.x + threadIdx.x;
    if (i < ni) pi[i] = 0;
    if (i < nf) pf[i] = 0.f;
}

// ---------------------------------------------------------------------------
// CSR build: histogram -> block scan -> scan bsums -> apply -> scatter
// ---------------------------------------------------------------------------
__global__ void hist_dst(const int* __restrict__ dst, int* __restrict__ deg, int E) {
    int e = blockIdx.x * blockDim.x + threadIdx.x;
    if (e < E) atomicAdd(&deg[dst[e]], 1);
}

__global__ void scan1(const int* __restrict__ deg, int* __restrict__ rowptr,
                      int* __restrict__ bsum, int N) {
    __shared__ int sh[256];
    int t = threadIdx.x, idx = blockIdx.x * 256 + t;
    sh[t] = (idx < N) ? deg[idx] : 0;
    __syncthreads();
    for (int off = 1; off < 256; off <<= 1) {
        int v = (t >= off) ? sh[t - off] : 0;
        __syncthreads();
        sh[t] += v;
        __syncthreads();
    }
    if (idx < N) rowptr[idx + 1] = sh[t];
    if (t == 255) bsum[blockIdx.x] = sh[255];
}

__global__ void scan2(int* __restrict__ bsum, int nb) {
    __shared__ int sh[512];
    int t = threadIdx.x;
    int orig = (t < nb) ? bsum[t] : 0;
    sh[t] = orig;
    __syncthreads();
    for (int off = 1; off < 512; off <<= 1) {
        int v = (t >= off) ? sh[t - off] : 0;
        __syncthreads();
        sh[t] += v;
        __syncthreads();
    }
    if (t < nb) bsum[t] = sh[t] - orig;   // exclusive
}

__global__ void scan3(int* __restrict__ rowptr, int* __restrict__ cursor,
                      const int* __restrict__ bsum, int N) {
    int idx = blockIdx.x * blockDim.x + threadIdx.x;
    if (idx >= N) return;
    int v = rowptr[idx + 1] + bsum[idx >> 8];
    rowptr[idx + 1] = v;
    if (idx + 1 < N) cursor[idx + 1] = v;
    if (idx == 0) { rowptr[0] = 0; cursor[0] = 0; }
}

__global__ void scatter_edges(const int* __restrict__ src, const int* __restrict__ dst,
                              int* __restrict__ cursor, int* __restrict__ col, int E) {
    int e = blockIdx.x * blockDim.x + threadIdx.x;
    if (e >= E) return;
    int pos = atomicAdd(&cursor[dst[e]], 1);
    col[pos] = src[e];
}

// ---------------------------------------------------------------------------
// CSR gather (bf16 in, bf16 out): agg[i] = h[i] + sum_nbr h.  One wave/node,
// 4B/lane packed bf16 pairs, fp32 accumulate, x4 unrolled edge loop.
// ---------------------------------------------------------------------------
__device__ __forceinline__ float2 upk(uint_t u) {
    float2 r; r.x = bf2f((ushort_t)(u & 0xffffu)); r.y = bf2f((ushort_t)(u >> 16));
    return r;
}

__global__ __launch_bounds__(256) void agg_gather(const ushort_t* __restrict__ h,
                                                  const int* __restrict__ rowptr,
                                                  const int* __restrict__ col,
                                                  ushort_t* __restrict__ agg, int N) {
    int w = (blockIdx.x * 256 + threadIdx.x) >> 6;   // node = wave id
    if (w >= N) return;
    int lane = threadIdx.x & 63;
    const uint_t* hp = (const uint_t*)h;
    float2 acc = upk(hp[(size_t)w * 64 + lane]);
    int st = rowptr[w], en = rowptr[w + 1];
    int e = st;
    for (; e + 4 <= en; e += 4) {
        int s0 = col[e], s1 = col[e + 1], s2 = col[e + 2], s3 = col[e + 3];
        float2 v0 = upk(hp[(size_t)s0 * 64 + lane]);
        float2 v1 = upk(hp[(size_t)s1 * 64 + lane]);
        float2 v2 = upk(hp[(size_t)s2 * 64 + lane]);
        float2 v3 = upk(hp[(size_t)s3 * 64 + lane]);
        acc.x += v0.x + v1.x + v2.x + v3.x;
        acc.y += v0.y + v1.y + v2.y + v3.y;
    }
    for (; e < en; ++e) {
        float2 v = upk(hp[(size_t)col[e] * 64 + lane]);
        acc.x += v.x; acc.y += v.y;
    }
    uint_t o = (uint_t)f2bf(acc.x) | ((uint_t)f2bf(acc.y) << 16);
    ((uint_t*)agg)[(size_t)w * 64 + lane] = o;
}

// ---------------------------------------------------------------------------
// Pack 4 [128,128] fp32 weight matrices into MFMA B-frag layout (bf16).
// out[m][chunk][ct][lane][i] = bf16(W[k][n]),
//   k = chunk*32 + (lane>>4)*8 + i,  n = ct*16 + (lane&15)
// ---------------------------------------------------------------------------
__global__ void pack_w(const float* __restrict__ w0, const float* __restrict__ w1,
                       const float* __restrict__ w2, const float* __restrict__ w3,
                       ushort_t* __restrict__ out) {
    int id = blockIdx.x * blockDim.x + threadIdx.x;   // 4*16384 total
    if (id >= 4 * 16384) return;
    int m = id >> 14, r = id & 16383;
    const float* w = (m == 0) ? w0 : (m == 1) ? w1 : (m == 2) ? w2 : w3;
    int i = r & 7, lane = (r >> 3) & 63, ct = (r >> 9) & 7, ch = r >> 12;
    int k = ch * 32 + ((lane >> 4) << 3) + i;
    int n = ct * 16 + (lane & 15);
    out[m * 16384 + r] = f2bf(w[k * 128 + n]);
}

// ---------------------------------------------------------------------------
// Code branch: per-graph 3-layer MLP + log_softmax(64) -> code_emb fp32 [G,64]
// ---------------------------------------------------------------------------
__global__ void code_branch(const float* __restrict__ cx,
                            const float* __restrict__ w1, const float* __restrict__ b1,
                            const float* __restrict__ w2, const float* __restrict__ b2,
                            const float* __restrict__ w3, const float* __restrict__ b3,
                            float* __restrict__ code_emb) {
    int g = blockIdx.x, j = threadIdx.x;   // 128 threads
    __shared__ float xb[128], h[128];
    xb[j] = cx[(size_t)g * 128 + j];
    __syncthreads();
    float acc = b1[j];
    for (int k = 0; k < 128; ++k) acc += xb[k] * w1[k * 128 + j];
    h[j] = fmaxf(acc, 0.f);
    __syncthreads();
    acc = b2[j];
    for (int k = 0; k < 128; ++k) acc += h[k] * w2[k * 128 + j];
    __syncthreads();
    xb[j] = fmaxf(acc, 0.f);
    __syncthreads();
    if (j < 64) {   // exactly wave 0
        float o = b3[j];
        for (int k = 0; k < 128; ++k) o += xb[k] * w3[k * 64 + j];
        float m = o;
        for (int off = 32; off; off >>= 1) m = fmaxf(m, __shfl_xor(m, off));
        float e = expf(o - m), s = e;
        for (int off = 32; off; off >>= 1) s += __shfl_xor(s, off);
        float lse = m + logf(s);
        code_emb[(size_t)g * 64 + j] = o - lse;
    }
}

// ---------------------------------------------------------------------------
// GEMM (bf16 in / bf16 out / single-bf16 weights): Y = f(A) @ W + bias.
// Core: block = 128 rows; col-split waves (2 col-tiles each); 8 B-frags
// (32 VGPR) hoisted; A double-buffered across 8 subtiles; 1 MFMA per
// (K-chunk, col-tile).
// launch_bounds(256,2) is FINAL (sweep: (256,3)=+15us/gemm x2, (256,4)=B
// dropped/FETCH 187MB; see r12-r15).
// BNA: BN params computed IN-KERNEL from stats+gamma+beta into LDS (fused
// bn_final -- saves 2 launches), then unpack->BN+relu->repack on A.
// STATS: fp32 col sum/sumsq via shfl + device atomics.
// ---------------------------------------------------------------------------
template <bool RELU, bool BNA, bool STATS>
__global__ __launch_bounds__(256, 2) void gemm128(const ushort_t* __restrict__ A,
                                                  const ushort_t* __restrict__ Bp,
                                                  const float* __restrict__ bias,
                                                  const float* __restrict__ stats_in,
                                                  const float* __restrict__ gamma,
                                                  const float* __restrict__ beta,
                                                  ushort_t* __restrict__ Y,
                                                  float* __restrict__ stats,
                                                  int Nrows) {
    __shared__ float bnps[BNA ? 256 : 1];
    int wave = threadIdx.x >> 6, lane = threadIdx.x & 63;
    int quad = lane >> 4, l16 = lane & 15;
    int rbase = blockIdx.x * 128;

    if (BNA) {
        if (threadIdx.x < 128) {
            int j = threadIdx.x;
            float s = stats_in[j], ss = stats_in[128 + j];
            float inv_n = 1.0f / (float)Nrows;
            float mu = s * inv_n;
            float var = fmaxf(ss * inv_n - mu * mu, 0.f);
            float sc = gamma[j] * rsqrtf(var + 1e-5f);
            bnps[j] = sc;
            bnps[128 + j] = beta[j] - mu * sc;
        }
        __syncthreads();
    }

    // ---- hoist this wave's 8 B-frags ----
    const short8* bp = (const short8*)Bp;
    short8 b[4][2];
#pragma unroll
    for (int c = 0; c < 4; ++c)
#pragma unroll
        for (int t = 0; t < 2; ++t)
            b[c][t] = bp[(c * 8 + wave * 2 + t) * 64 + lane];
    float bsv[2] = { bias[(wave * 2) * 16 + l16], bias[(wave * 2 + 1) * 16 + l16] };

    float cs[2] = {0.f, 0.f}, css[2] = {0.f, 0.f};
    short8 a[2][4];   // double buffer: 4 K-chunk frags per subtile

    // prefetch sub 0
    {
        int arow = rbase + l16;
        if (arow < Nrows) {
            const short8* ap = (const short8*)(A + (size_t)arow * 128);
#pragma unroll
            for (int c = 0; c < 4; ++c) a[0][c] = ap[c * 4 + quad];
        } else {
#pragma unroll
            for (int c = 0; c < 4; ++c) a[0][c] = (short8)0;
        }
    }

#pragma unroll 2
    for (int sub = 0; sub < 8; ++sub) {
        int cur = sub & 1, nxt = cur ^ 1;
        if (sub + 1 < 8) {
            int arow = rbase + (sub + 1) * 16 + l16;
            if (arow < Nrows) {
                const short8* ap = (const short8*)(A + (size_t)arow * 128);
#pragma unroll
                for (int c = 0; c < 4; ++c) a[nxt][c] = ap[c * 4 + quad];
            } else {
#pragma unroll
                for (int c = 0; c < 4; ++c) a[nxt][c] = (short8)0;
            }
        }
        short8 af[4];
#pragma unroll
        for (int c = 0; c < 4; ++c) {
            if (BNA) {
                int cbase = c * 32 + quad * 8;
#pragma unroll
                for (int i = 0; i < 8; ++i) {
                    float x = bf2f((ushort_t)a[cur][c][i]);
                    x = fmaxf(x * bnps[cbase + i] + bnps[128 + cbase + i], 0.f);
                    af[c][i] = (short)f2bf(x);
                }
            } else {
                af[c] = a[cur][c];
            }
        }
        f32x4 acc[2] = {};
#pragma unroll
        for (int c = 0; c < 4; ++c)
#pragma unroll
            for (int t = 0; t < 2; ++t)
                acc[t] = __builtin_amdgcn_mfma_f32_16x16x32_bf16(af[c], b[c][t], acc[t], 0, 0, 0);
#pragma unroll
        for (int t = 0; t < 2; ++t) {
            int colj = (wave * 2 + t) * 16 + l16;
#pragma unroll
            for (int i = 0; i < 4; ++i) {
                int row = rbase + sub * 16 + quad * 4 + i;
                if (row < Nrows) {
                    float v = acc[t][i] + bsv[t];
                    if (RELU) v = fmaxf(v, 0.f);
                    Y[(size_t)row * 128 + colj] = f2bf(v);
                    if (STATS) { cs[t] += v; css[t] += v * v; }
                }
            }
        }
    }
    if (STATS) {
#pragma unroll
        for (int t = 0; t < 2; ++t) {
            float s = cs[t], q = css[t];
            s += __shfl_xor(s, 16); q += __shfl_xor(q, 16);
            s += __shfl_xor(s, 32); q += __shfl_xor(q, 32);
            if (quad == 0) {
                int colj = (wave * 2 + t) * 16 + l16;
                unsafeAtomicAdd(&stats[colj], s);
                unsafeAtomicAdd(&stats[128 + colj], q);
            }
        }
    }
}

// ---------------------------------------------------------------------------
// Fused pool (sorted-batch binary search, bf16 H) + head MLP + concat +
// final log_softmax  (fp32 math throughout)
// ---------------------------------------------------------------------------
__global__ void head_kernel(const ushort_t* __restrict__ H, const int* __restrict__ batch,
                            const float* __restrict__ code_emb,
                            const float* __restrict__ l1w, const float* __restrict__ l1b,
                            const float* __restrict__ l2w, const float* __restrict__ l2b,
                            const float* __restrict__ finw, const float* __restrict__ finb,
                            float* __restrict__ out, int Nrows) {
    int g = blockIdx.x, j = threadIdx.x;   // 128 threads
    int lo = 0, hi = Nrows;
    while (lo < hi) { int m = (lo + hi) >> 1; if (batch[m] < g) lo = m + 1; else hi = m; }
    int st = lo;
    hi = Nrows;
    while (lo < hi) { int m = (lo + hi) >> 1; if (batch[m] <= g) lo = m + 1; else hi = m; }
    int en = lo;

    float p = 0.f;
    int i = st;
    for (; i + 4 <= en; i += 4) {
        float v0 = bf2f(H[(size_t)i * 128 + j]);
        float v1 = bf2f(H[(size_t)(i + 1) * 128 + j]);
        float v2 = bf2f(H[(size_t)(i + 2) * 128 + j]);
        float v3 = bf2f(H[(size_t)(i + 3) * 128 + j]);
        p += v0 + v1 + v2 + v3;
    }
    for (; i < en; ++i) p += bf2f(H[(size_t)i * 128 + j]);

    __shared__ float pb[128], t[128], v[128], lg[2];
    pb[j] = p;
    __syncthreads();
    float acc = l1b[j];
    for (int k = 0; k < 128; ++k) acc += pb[k] * l1w[k * 128 + j];
    t[j] = fmaxf(acc, 0.f);
    __syncthreads();
    if (j < 64) {
        float a2 = l2b[j];
        for (int k = 0; k < 128; ++k) a2 += t[k] * l2w[k * 64 + j];
        v[64 + j] = a2;                       // trans_emb
        v[j] = code_emb[(size_t)g * 64 + j];  // code_emb
    }
    __syncthreads();
    if (j < 2) {
        float a3 = finb[j];
        for (int k = 0; k < 128; ++k) a3 += v[k] * finw[k * 2 + j];
        lg[j] = a3;
    }
    __syncthreads();
    if (j == 0) {
        float a = lg[0], b = lg[1];
        float m = fmaxf(a, b);
        float lse = m + logf(expf(a - m) + expf(b - m));
        out[g * 2 + 0] = a - lse;
        out[g * 2 + 1] = b - lse;
    }
}

// ---------------------------------------------------------------------------

extern "C" void kernel_launch(void* const* d_in, const int* in_sizes, int n_in,
                              void* d_out, int out_size, void* d_ws, size_t ws_size,
                              hipStream_t stream) {
    (void)n_in; (void)out_size; (void)ws_size;
    const float* x     = (const float*)d_in[0];
    const int*   ei    = (const int*)d_in[1];
    const int*   batch = (const int*)d_in[2];
    const float* cx    = (const float*)d_in[3];
    const float* c1w1  = (const float*)d_in[4];
    const float* c1b1  = (const float*)d_in[5];
    const float* c1g   = (const float*)d_in[6];
    const float* c1be  = (const float*)d_in[7];
    const float* c1w2  = (const float*)d_in[8];
    const float* c1b2  = (const float*)d_in[9];
    const float* c2w1  = (const float*)d_in[10];
    const float* c2b1  = (const float*)d_in[11];
    const float* c2g   = (const float*)d_in[12];
    const float* c2be  = (const float*)d_in[13];
    const float* c2w2  = (const float*)d_in[14];
    const float* c2b2  = (const float*)d_in[15];
    const float* gl1w  = (const float*)d_in[16];
    const float* gl1b  = (const float*)d_in[17];
    const float* gl2w  = (const float*)d_in[18];
    const float* gl2b  = (const float*)d_in[19];
    const float* fc1w  = (const float*)d_in[20];
    const float* fc1b  = (const float*)d_in[21];
    const float* fc2w  = (const float*)d_in[22];
    const float* fc2b  = (const float*)d_in[23];
    const float* fc3w  = (const float*)d_in[24];
    const float* fc3b  = (const float*)d_in[25];
    const float* finw  = (const float*)d_in[26];
    const float* finb  = (const float*)d_in[27];

    const int N = in_sizes[0] / 128;
    const int E = in_sizes[1] / 2;
    const int G = in_sizes[3] / 128;
    const int* src = ei;
    const int* dst = ei + E;

    // workspace layout (16B-aligned)
    ushort_t* bufA = (ushort_t*)d_ws;                  // N*128 bf16
    ushort_t* bufB = bufA + (size_t)N * 128;           // N*128 bf16
    float* code_emb = (float*)(bufB + (size_t)N * 128); // G*64
    float* statsA   = code_emb + (size_t)G * 64;       // 256
    float* statsB   = statsA + 256;                    // 256
    ushort_t* packW = (ushort_t*)(statsB + 256);       // 4*16384 ushorts
    int* rowptr = (int*)(packW + 4 * 16384);           // N+1
    int* tmp    = rowptr + (N + 1);                    // N+1 (deg, then cursor)
    int* bsum   = tmp + (N + 1);                       // 512
    int* col    = bsum + 512;                          // E

    const int gmm = (N + 127) / 128;
    const int nb  = (N + 255) / 256;                   // scan chunks (<=512)
    const int gag = (N * 64 + 255) / 256;              // gather: 1 wave/node

    // ---- x -> bf16 (into bufB; consumed by conv1 gather) ----
    cvt_f32_bf16<<<(N * 64 + 255) / 256, 256, 0, stream>>>(
        (const float2*)x, (uint_t*)bufB, N * 64);

    // ---- CSR build + init (once) ----
    init_zero<<<(N + 256) / 256, 256, 0, stream>>>(tmp, N + 1, statsA, 512);
    hist_dst<<<(E + 255) / 256, 256, 0, stream>>>(dst, tmp, E);
    scan1<<<nb, 256, 0, stream>>>(tmp, rowptr, bsum, N);
    scan2<<<1, 512, 0, stream>>>(bsum, nb);
    scan3<<<(N + 255) / 256, 256, 0, stream>>>(rowptr, tmp, bsum, N);
    scatter_edges<<<(E + 255) / 256, 256, 0, stream>>>(src, dst, tmp, col, E);

    pack_w<<<(4 * 16384 + 255) / 256, 256, 0, stream>>>(c1w1, c1w2, c2w1, c2w2, packW);
    code_branch<<<G, 128, 0, stream>>>(cx, fc1w, fc1b, fc2w, fc2b, fc3w, fc3b, code_emb);

    // ---- conv1 ----
    agg_gather<<<gag, 256, 0, stream>>>(bufB, rowptr, col, bufA, N);            // agg1
    gemm128<false, false, true><<<gmm, 256, 0, stream>>>(
        bufA, packW, c1b1, nullptr, nullptr, nullptr, bufB, statsA, N);         // y1 + stats
    gemm128<true, true, false><<<gmm, 256, 0, stream>>>(
        bufB, packW + 16384, c1b2, statsA, c1g, c1be, bufA, nullptr, N);        // h1 (BN fused)

    // ---- conv2 ----
    agg_gather<<<gag, 256, 0, stream>>>(bufA, rowptr, col, bufB, N);            // agg2
    gemm128<false, false, true><<<gmm, 256, 0, stream>>>(
        bufB, packW + 2 * 16384, c2b1, nullptr, nullptr, nullptr, bufA, statsB, N); // y2 + stats
    gemm128<true, true, false><<<gmm, 256, 0, stream>>>(
        bufA, packW + 3 * 16384, c2b2, statsB, c2g, c2be, bufB, nullptr, N);    // h2 (BN fused)

    head_kernel<<<G, 128, 0, stream>>>(bufB, batch, code_emb,
                                       gl1w, gl1b, gl2w, gl2b, finw, finb,
                                       (float*)d_out, N);
}

// Round 18
// 421.235 us; speedup vs baseline: 1.0944x; 1.0202x over previous
//
#include <hip/hip_runtime.h>

typedef unsigned short ushort_t;
typedef unsigned int uint_t;
typedef __attribute__((ext_vector_type(8))) short short8;
typedef __attribute__((ext_vector_type(4))) float f32x4;

__device__ __forceinline__ float bf2f(ushort_t u) {
    union { unsigned u; float f; } c; c.u = ((unsigned)u) << 16; return c.f;
}
__device__ __forceinline__ ushort_t f2bf(float f) {
    union { float f; unsigned u; } c; c.f = f;
    unsigned u = c.u;
    u += 0x7fffu + ((u >> 16) & 1u);   // RNE
    return (ushort_t)(u >> 16);
}
__device__ __forceinline__ float2 upk(uint_t u) {
    float2 r; r.x = bf2f((ushort_t)(u & 0xffffu)); r.y = bf2f((ushort_t)(u >> 16));
    return r;
}

// ---------------------------------------------------------------------------
// PREP (fused, independent sections partitioned by blockIdx):
//   [0, cvtB)              : x fp32 -> bf16 (2 elems/thread)
//   [cvtB, cvtB+initB)     : zero deg[N+1] + stats[512]
//   [+initB, +initB+256)   : pack 4 weight matrices into MFMA B-frag bf16
//   [.., +G)               : code-branch per-graph MLP + log_softmax
// Saves 3 launches + gaps vs separate kernels (all were serialized).
// ---------------------------------------------------------------------------
__global__ __launch_bounds__(256) void prep(
    // cvt
    const float2* __restrict__ x2, uint_t* __restrict__ xbf, int n2, int cvtB,
    // init
    int* __restrict__ deg, int ni, float* __restrict__ stats0, int initB,
    // pack
    const float* __restrict__ w0, const float* __restrict__ w1,
    const float* __restrict__ w2, const float* __restrict__ w3,
    ushort_t* __restrict__ packW,
    // code branch
    const float* __restrict__ cx,
    const float* __restrict__ cw1, const float* __restrict__ cb1,
    const float* __restrict__ cw2, const float* __restrict__ cb2,
    const float* __restrict__ cw3, const float* __restrict__ cb3,
    float* __restrict__ code_emb) {
    __shared__ float xb[128], h[128];
    int blk = blockIdx.x, tid = threadIdx.x;

    if (blk < cvtB) {                      // ---- cvt ----
        int i = blk * 256 + tid;
        if (i < n2) {
            float2 v = x2[i];
            xbf[i] = (uint_t)f2bf(v.x) | ((uint_t)f2bf(v.y) << 16);
        }
        return;
    }
    blk -= cvtB;
    if (blk < initB) {                     // ---- init ----
        int i = blk * 256 + tid;
        if (i < ni) deg[i] = 0;
        if (i < 512) stats0[i] = 0.f;
        return;
    }
    blk -= initB;
    if (blk < 256) {                       // ---- pack_w ----
        int id = blk * 256 + tid;          // 4*16384 total
        int m = id >> 14, r = id & 16383;
        const float* w = (m == 0) ? w0 : (m == 1) ? w1 : (m == 2) ? w2 : w3;
        int i = r & 7, lane = (r >> 3) & 63, ct = (r >> 9) & 7, ch = r >> 12;
        int k = ch * 32 + ((lane >> 4) << 3) + i;
        int n = ct * 16 + (lane & 15);
        packW[m * 16384 + r] = f2bf(w[k * 128 + n]);
        return;
    }
    blk -= 256;
    {                                      // ---- code branch (g = blk) ----
        int g = blk, j = tid;
        if (j < 128) xb[j] = cx[(size_t)g * 128 + j];
        __syncthreads();
        float acc = 0.f;
        if (j < 128) {
            acc = cb1[j];
            for (int k = 0; k < 128; ++k) acc += xb[k] * cw1[k * 128 + j];
        }
        __syncthreads();
        if (j < 128) h[j] = fmaxf(acc, 0.f);
        __syncthreads();
        if (j < 128) {
            acc = cb2[j];
            for (int k = 0; k < 128; ++k) acc += h[k] * cw2[k * 128 + j];
        }
        __syncthreads();
        if (j < 128) xb[j] = fmaxf(acc, 0.f);
        __syncthreads();
        if (j < 64) {
            float o = cb3[j];
            for (int k = 0; k < 128; ++k) o += xb[k] * cw3[k * 64 + j];
            float m = o;
            for (int off = 32; off; off >>= 1) m = fmaxf(m, __shfl_xor(m, off));
            float e = expf(o - m), s = e;
            for (int off = 32; off; off >>= 1) s += __shfl_xor(s, off);
            float lse = m + logf(s);
            code_emb[(size_t)g * 64 + j] = o - lse;
        }
    }
}

// ---------------------------------------------------------------------------
// CSR build: histogram -> per-chunk scan -> (scan bsum + apply, merged) ->
// scatter
// ---------------------------------------------------------------------------
__global__ void hist_dst(const int* __restrict__ dst, int* __restrict__ deg, int E) {
    int e = blockIdx.x * blockDim.x + threadIdx.x;
    if (e < E) atomicAdd(&deg[dst[e]], 1);
}

__global__ void scan1(const int* __restrict__ deg, int* __restrict__ rowptr,
                      int* __restrict__ bsum, int N) {
    __shared__ int sh[256];
    int t = threadIdx.x, idx = blockIdx.x * 256 + t;
    sh[t] = (idx < N) ? deg[idx] : 0;
    __syncthreads();
    for (int off = 1; off < 256; off <<= 1) {
        int v = (t >= off) ? sh[t - off] : 0;
        __syncthreads();
        sh[t] += v;
        __syncthreads();
    }
    if (idx < N) rowptr[idx + 1] = sh[t];
    if (t == 255) bsum[blockIdx.x] = sh[255];
}

// merged scan2+scan3: each block computes exclusive prefix of bsum[0..blk)
// itself (<=512 L2-resident ints, block reduce), then applies to its chunk.
__global__ void scan23(int* __restrict__ rowptr, int* __restrict__ cursor,
                       const int* __restrict__ bsum, int N) {
    __shared__ int red[256];
    int b = blockIdx.x, t = threadIdx.x;
    int s = 0;
    for (int i = t; i < b; i += 256) s += bsum[i];
    red[t] = s;
    __syncthreads();
    for (int off = 128; off; off >>= 1) {
        if (t < off) red[t] += red[t + off];
        __syncthreads();
    }
    int base = red[0];
    int idx = b * 256 + t;
    if (idx >= N) return;
    int v = rowptr[idx + 1] + base;
    rowptr[idx + 1] = v;
    if (idx + 1 < N) cursor[idx + 1] = v;
    if (idx == 0) { rowptr[0] = 0; cursor[0] = 0; }
}

__global__ void scatter_edges(const int* __restrict__ src, const int* __restrict__ dst,
                              int* __restrict__ cursor, int* __restrict__ col, int E) {
    int e = blockIdx.x * blockDim.x + threadIdx.x;
    if (e >= E) return;
    int pos = atomicAdd(&cursor[dst[e]], 1);
    col[pos] = src[e];
}

// ---------------------------------------------------------------------------
// CSR gather (bf16 in, bf16 out): agg[i] = h[i] + sum_nbr h.  One wave/node,
// 4B/lane packed bf16 pairs, fp32 accumulate, x4 unrolled edge loop.
// ---------------------------------------------------------------------------
__global__ __launch_bounds__(256) void agg_gather(const ushort_t* __restrict__ h,
                                                  const int* __restrict__ rowptr,
                                                  const int* __restrict__ col,
                                                  ushort_t* __restrict__ agg, int N) {
    int w = (blockIdx.x * 256 + threadIdx.x) >> 6;   // node = wave id
    if (w >= N) return;
    int lane = threadIdx.x & 63;
    const uint_t* hp = (const uint_t*)h;
    float2 acc = upk(hp[(size_t)w * 64 + lane]);
    int st = rowptr[w], en = rowptr[w + 1];
    int e = st;
    for (; e + 4 <= en; e += 4) {
        int s0 = col[e], s1 = col[e + 1], s2 = col[e + 2], s3 = col[e + 3];
        float2 v0 = upk(hp[(size_t)s0 * 64 + lane]);
        float2 v1 = upk(hp[(size_t)s1 * 64 + lane]);
        float2 v2 = upk(hp[(size_t)s2 * 64 + lane]);
        float2 v3 = upk(hp[(size_t)s3 * 64 + lane]);
        acc.x += v0.x + v1.x + v2.x + v3.x;
        acc.y += v0.y + v1.y + v2.y + v3.y;
    }
    for (; e < en; ++e) {
        float2 v = upk(hp[(size_t)col[e] * 64 + lane]);
        acc.x += v.x; acc.y += v.y;
    }
    uint_t o = (uint_t)f2bf(acc.x) | ((uint_t)f2bf(acc.y) << 16);
    ((uint_t*)agg)[(size_t)w * 64 + lane] = o;
}

// ---------------------------------------------------------------------------
// GEMM (bf16 in / bf16 out / single-bf16 weights): Y = f(A) @ W + bias.
// Core: block = 128 rows; col-split waves (2 col-tiles each); 8 B-frags
// (32 VGPR) hoisted; A double-buffered across 8 subtiles; 1 MFMA per
// (K-chunk, col-tile).
// launch_bounds(256,2) is FINAL (sweep r12-r15: (256,3)=+15us/gemm spill,
// (256,4)=B dropped / FETCH 187MB).
// BNA: BN params computed IN-KERNEL from stats+gamma+beta into LDS, then
// unpack->BN+relu->repack on A. STATS: fp32 col sum/sumsq via shfl+atomics.
// ---------------------------------------------------------------------------
template <bool RELU, bool BNA, bool STATS>
__global__ __launch_bounds__(256, 2) void gemm128(const ushort_t* __restrict__ A,
                                                  const ushort_t* __restrict__ Bp,
                                                  const float* __restrict__ bias,
                                                  const float* __restrict__ stats_in,
                                                  const float* __restrict__ gamma,
                                                  const float* __restrict__ beta,
                                                  ushort_t* __restrict__ Y,
                                                  float* __restrict__ stats,
                                                  int Nrows) {
    __shared__ float bnps[BNA ? 256 : 1];
    int wave = threadIdx.x >> 6, lane = threadIdx.x & 63;
    int quad = lane >> 4, l16 = lane & 15;
    int rbase = blockIdx.x * 128;

    if (BNA) {
        if (threadIdx.x < 128) {
            int j = threadIdx.x;
            float s = stats_in[j], ss = stats_in[128 + j];
            float inv_n = 1.0f / (float)Nrows;
            float mu = s * inv_n;
            float var = fmaxf(ss * inv_n - mu * mu, 0.f);
            float sc = gamma[j] * rsqrtf(var + 1e-5f);
            bnps[j] = sc;
            bnps[128 + j] = beta[j] - mu * sc;
        }
        __syncthreads();
    }

    // ---- hoist this wave's 8 B-frags ----
    const short8* bp = (const short8*)Bp;
    short8 b[4][2];
#pragma unroll
    for (int c = 0; c < 4; ++c)
#pragma unroll
        for (int t = 0; t < 2; ++t)
            b[c][t] = bp[(c * 8 + wave * 2 + t) * 64 + lane];
    float bsv[2] = { bias[(wave * 2) * 16 + l16], bias[(wave * 2 + 1) * 16 + l16] };

    float cs[2] = {0.f, 0.f}, css[2] = {0.f, 0.f};
    short8 a[2][4];   // double buffer: 4 K-chunk frags per subtile

    // prefetch sub 0
    {
        int arow = rbase + l16;
        if (arow < Nrows) {
            const short8* ap = (const short8*)(A + (size_t)arow * 128);
#pragma unroll
            for (int c = 0; c < 4; ++c) a[0][c] = ap[c * 4 + quad];
        } else {
#pragma unroll
            for (int c = 0; c < 4; ++c) a[0][c] = (short8)0;
        }
    }

#pragma unroll 2
    for (int sub = 0; sub < 8; ++sub) {
        int cur = sub & 1, nxt = cur ^ 1;
        if (sub + 1 < 8) {
            int arow = rbase + (sub + 1) * 16 + l16;
            if (arow < Nrows) {
                const short8* ap = (const short8*)(A + (size_t)arow * 128);
#pragma unroll
                for (int c = 0; c < 4; ++c) a[nxt][c] = ap[c * 4 + quad];
            } else {
#pragma unroll
                for (int c = 0; c < 4; ++c) a[nxt][c] = (short8)0;
            }
        }
        short8 af[4];
#pragma unroll
        for (int c = 0; c < 4; ++c) {
            if (BNA) {
                int cbase = c * 32 + quad * 8;
#pragma unroll
                for (int i = 0; i < 8; ++i) {
                    float x = bf2f((ushort_t)a[cur][c][i]);
                    x = fmaxf(x * bnps[cbase + i] + bnps[128 + cbase + i], 0.f);
                    af[c][i] = (short)f2bf(x);
                }
            } else {
                af[c] = a[cur][c];
            }
        }
        f32x4 acc[2] = {};
#pragma unroll
        for (int c = 0; c < 4; ++c)
#pragma unroll
            for (int t = 0; t < 2; ++t)
                acc[t] = __builtin_amdgcn_mfma_f32_16x16x32_bf16(af[c], b[c][t], acc[t], 0, 0, 0);
#pragma unroll
        for (int t = 0; t < 2; ++t) {
            int colj = (wave * 2 + t) * 16 + l16;
#pragma unroll
            for (int i = 0; i < 4; ++i) {
                int row = rbase + sub * 16 + quad * 4 + i;
                if (row < Nrows) {
                    float v = acc[t][i] + bsv[t];
                    if (RELU) v = fmaxf(v, 0.f);
                    Y[(size_t)row * 128 + colj] = f2bf(v);
                    if (STATS) { cs[t] += v; css[t] += v * v; }
                }
            }
        }
    }
    if (STATS) {
#pragma unroll
        for (int t = 0; t < 2; ++t) {
            float s = cs[t], q = css[t];
            s += __shfl_xor(s, 16); q += __shfl_xor(q, 16);
            s += __shfl_xor(s, 32); q += __shfl_xor(q, 32);
            if (quad == 0) {
                int colj = (wave * 2 + t) * 16 + l16;
                unsafeAtomicAdd(&stats[colj], s);
                unsafeAtomicAdd(&stats[128 + colj], q);
            }
        }
    }
}

// ---------------------------------------------------------------------------
// Fused pool (sorted-batch binary search, bf16 H) + head MLP + concat +
// final log_softmax  (fp32 math throughout)
// ---------------------------------------------------------------------------
__global__ void head_kernel(const ushort_t* __restrict__ H, const int* __restrict__ batch,
                            const float* __restrict__ code_emb,
                            const float* __restrict__ l1w, const float* __restrict__ l1b,
                            const float* __restrict__ l2w, const float* __restrict__ l2b,
                            const float* __restrict__ finw, const float* __restrict__ finb,
                            float* __restrict__ out, int Nrows) {
    int g = blockIdx.x, j = threadIdx.x;   // 128 threads
    int lo = 0, hi = Nrows;
    while (lo < hi) { int m = (lo + hi) >> 1; if (batch[m] < g) lo = m + 1; else hi = m; }
    int st = lo;
    hi = Nrows;
    while (lo < hi) { int m = (lo + hi) >> 1; if (batch[m] <= g) lo = m + 1; else hi = m; }
    int en = lo;

    float p = 0.f;
    int i = st;
    for (; i + 4 <= en; i += 4) {
        float v0 = bf2f(H[(size_t)i * 128 + j]);
        float v1 = bf2f(H[(size_t)(i + 1) * 128 + j]);
        float v2 = bf2f(H[(size_t)(i + 2) * 128 + j]);
        float v3 = bf2f(H[(size_t)(i + 3) * 128 + j]);
        p += v0 + v1 + v2 + v3;
    }
    for (; i < en; ++i) p += bf2f(H[(size_t)i * 128 + j]);

    __shared__ float pb[128], t[128], v[128], lg[2];
    pb[j] = p;
    __syncthreads();
    float acc = l1b[j];
    for (int k = 0; k < 128; ++k) acc += pb[k] * l1w[k * 128 + j];
    t[j] = fmaxf(acc, 0.f);
    __syncthreads();
    if (j < 64) {
        float a2 = l2b[j];
        for (int k = 0; k < 128; ++k) a2 += t[k] * l2w[k * 64 + j];
        v[64 + j] = a2;                       // trans_emb
        v[j] = code_emb[(size_t)g * 64 + j];  // code_emb
    }
    __syncthreads();
    if (j < 2) {
        float a3 = finb[j];
        for (int k = 0; k < 128; ++k) a3 += v[k] * finw[k * 2 + j];
        lg[j] = a3;
    }
    __syncthreads();
    if (j == 0) {
        float a = lg[0], b = lg[1];
        float m = fmaxf(a, b);
        float lse = m + logf(expf(a - m) + expf(b - m));
        out[g * 2 + 0] = a - lse;
        out[g * 2 + 1] = b - lse;
    }
}

// ---------------------------------------------------------------------------

extern "C" void kernel_launch(void* const* d_in, const int* in_sizes, int n_in,
                              void* d_out, int out_size, void* d_ws, size_t ws_size,
                              hipStream_t stream) {
    (void)n_in; (void)out_size; (void)ws_size;
    const float* x     = (const float*)d_in[0];
    const int*   ei    = (const int*)d_in[1];
    const int*   batch = (const int*)d_in[2];
    const float* cx    = (const float*)d_in[3];
    const float* c1w1  = (const float*)d_in[4];
    const float* c1b1  = (const float*)d_in[5];
    const float* c1g   = (const float*)d_in[6];
    const float* c1be  = (const float*)d_in[7];
    const float* c1w2  = (const float*)d_in[8];
    const float* c1b2  = (const float*)d_in[9];
    const float* c2w1  = (const float*)d_in[10];
    const float* c2b1  = (const float*)d_in[11];
    const float* c2g   = (const float*)d_in[12];
    const float* c2be  = (const float*)d_in[13];
    const float* c2w2  = (const float*)d_in[14];
    const float* c2b2  = (const float*)d_in[15];
    const float* gl1w  = (const float*)d_in[16];
    const float* gl1b  = (const float*)d_in[17];
    const float* gl2w  = (const float*)d_in[18];
    const float* gl2b  = (const float*)d_in[19];
    const float* fc1w  = (const float*)d_in[20];
    const float* fc1b  = (const float*)d_in[21];
    const float* fc2w  = (const float*)d_in[22];
    const float* fc2b  = (const float*)d_in[23];
    const float* fc3w  = (const float*)d_in[24];
    const float* fc3b  = (const float*)d_in[25];
    const float* finw  = (const float*)d_in[26];
    const float* finb  = (const float*)d_in[27];

    const int N = in_sizes[0] / 128;
    const int E = in_sizes[1] / 2;
    const int G = in_sizes[3] / 128;
    const int* src = ei;
    const int* dst = ei + E;

    // workspace layout (16B-aligned)
    ushort_t* bufA = (ushort_t*)d_ws;                  // N*128 bf16
    ushort_t* bufB = bufA + (size_t)N * 128;           // N*128 bf16
    float* code_emb = (float*)(bufB + (size_t)N * 128); // G*64
    float* statsA   = code_emb + (size_t)G * 64;       // 256
    float* statsB   = statsA + 256;                    // 256
    ushort_t* packW = (ushort_t*)(statsB + 256);       // 4*16384 ushorts
    int* rowptr = (int*)(packW + 4 * 16384);           // N+1
    int* tmp    = rowptr + (N + 1);                    // N+1 (deg, then cursor)
    int* bsum   = tmp + (N + 1);                       // 512
    int* col    = bsum + 512;                          // E

    const int gmm = (N + 127) / 128;
    const int nb  = (N + 255) / 256;                   // scan chunks (<=512)
    const int gag = (N * 64 + 255) / 256;              // gather: 1 wave/node

    const int n2    = N * 64;
    const int cvtB  = (n2 + 255) / 256;
    const int initB = (N + 1 + 255) / 256;
    const int prepB = cvtB + initB + 256 + G;

    // ---- prep: cvt(x->bf16 into bufB) + zero(deg,stats) + pack_w + code ----
    prep<<<prepB, 256, 0, stream>>>((const float2*)x, (uint_t*)bufB, n2, cvtB,
                                    tmp, N + 1, statsA, initB,
                                    c1w1, c1w2, c2w1, c2w2, packW,
                                    cx, fc1w, fc1b, fc2w, fc2b, fc3w, fc3b, code_emb);

    // ---- CSR build ----
    hist_dst<<<(E + 255) / 256, 256, 0, stream>>>(dst, tmp, E);
    scan1<<<nb, 256, 0, stream>>>(tmp, rowptr, bsum, N);
    scan23<<<nb, 256, 0, stream>>>(rowptr, tmp, bsum, N);
    scatter_edges<<<(E + 255) / 256, 256, 0, stream>>>(src, dst, tmp, col, E);

    // ---- conv1 ----
    agg_gather<<<gag, 256, 0, stream>>>(bufB, rowptr, col, bufA, N);            // agg1
    gemm128<false, false, true><<<gmm, 256, 0, stream>>>(
        bufA, packW, c1b1, nullptr, nullptr, nullptr, bufB, statsA, N);         // y1 + stats
    gemm128<true, true, false><<<gmm, 256, 0, stream>>>(
        bufB, packW + 16384, c1b2, statsA, c1g, c1be, bufA, nullptr, N);        // h1 (BN fused)

    // ---- conv2 ----
    agg_gather<<<gag, 256, 0, stream>>>(bufA, rowptr, col, bufB, N);            // agg2
    gemm128<false, false, true><<<gmm, 256, 0, stream>>>(
        bufB, packW + 2 * 16384, c2b1, nullptr, nullptr, nullptr, bufA, statsB, N); // y2 + stats
    gemm128<true, true, false><<<gmm, 256, 0, stream>>>(
        bufA, packW + 3 * 16384, c2b2, statsB, c2g, c2be, bufB, nullptr, N);    // h2 (BN fused)

    head_kernel<<<G, 128, 0, stream>>>(bufB, batch, code_emb,
                                       gl1w, gl1b, gl2w, gl2b, finw, finb,
                                       (float*)d_out, N);
}